// Round 13
// baseline (131.041 us; speedup 1.0000x reference)
//
#include <hip/hip_runtime.h>

// Bilinear backward warp, NCHW f32 — pipelined LDS channel loop, depth-2.
// Block = 64x32 tile, 1024 threads. LDS: THREE buffers x 2 planes of (72x40)
// RAD=4 halo'd tile (69 KB). Phase p: issue DMA for phase p+2 (channels
// clamped past C-1 -> uniform count, dummy restages are L2 hits), gather
// buffer p%3, stores, then counted s_waitcnt vmcnt(10) (phase 0: 6) +
// raw s_barrier. Each DMA now has TWO phases of slack instead of one —
// removes the exposed HBM/L2 staging latency R11 stalled on each barrier.
// In-order vmcnt accounting: ops issued after D(p+1) = S(p-1)x4 + D(p+2)x2
// + S(p)x4 = 10. Stage-target buffer = gathered two phases ago (freed by
// the intervening barrier).

#define TSX 64
#define TSY 32
#define RAD 4
#define LW  (TSX + 2*RAD)     // 72
#define LH  (TSY + 2*RAD)     // 40
#define GPR (LW/4)            // 18 float4 groups per row
#define PLANE (LW*LH)         // 2880 floats = 11520 B
#define NV  (LH*GPR)          // 720 groups per plane
#define CGB 2                 // channels per buffer
#define BUFSZ (CGB*PLANE)
#define NSTG (CGB*NV)         // 1440 DMA slots per buffer
#define NTHREADS 1024
#define SOFF (NSTG - NTHREADS)  // 416: second-slot offset (lane-consecutive)

static_assert(NSTG >= NTHREADS && NSTG <= 2*NTHREADS, "2 slots per thread");

#define GLOAD_LDS16(g, l)                                                  \
    __builtin_amdgcn_global_load_lds(                                      \
        (const __attribute__((address_space(1))) void*)(g),                \
        (__attribute__((address_space(3))) void*)(l), 16, 0, 0)

__global__ __launch_bounds__(NTHREADS, 8) void warp_pipe4(
    const float* __restrict__ img,
    const float* __restrict__ flow,
    const int* __restrict__ Hp,
    const int* __restrict__ Wp,
    float* __restrict__ out,
    int HW, int C)
{
    __shared__ __align__(16) float lds[3 * BUFSZ];   // 69120 B

    const int W = *Wp;
    const int H = *Hp;
    const int tilesX = (W + TSX - 1) / TSX;
    const int tilesY = (H + TSY - 1) / TSY;
    const int ntiles = tilesX * tilesY;
    const int bid = blockIdx.x;
    if (bid >= ntiles) return;

    // bijective XCD band swizzle
    const int q = ntiles >> 3, r = ntiles & 7;
    const int xcd = bid & 7, sub = bid >> 3;
    const int t = (xcd < r ? xcd*(q+1) : r*(q+1) + (xcd-r)*q) + sub;

    const int tileY = t / tilesX;
    const int tileX = t - tileY * tilesX;
    const int gx0 = tileX * TSX - RAD;   // always ≡ 0 (mod 4)
    const int gy0 = tileY * TSY - RAD;

    const int tid = threadIdx.x;
    const int lx  = tid & 63;
    const int rw  = (tid >> 6) * 2;      // 2 rows per thread
    const int gx  = tileX * TSX + lx;

    const float Wm1 = (float)(W - 1);
    const float Hm1 = (float)(H - 1);

    // ---- per-pixel precompute (once per tile) ----
    float wtl[2], wth[2], wbl[2], wbh[2];
    int enc[2], pixk[2] = {0, 0};
    #pragma unroll
    for (int k = 0; k < 2; ++k) {
        const int gy = tileY * TSY + rw + k;
        enc[k] = -2;
        if (gx >= W || gy >= H) continue;
        const int pix = gy * W + gx;
        pixk[k] = pix;
        const float u = flow[pix];
        const float v = flow[HW + pix];

        // normalize/denormalize round-trip omitted (identity, +-1 ulp)
        const float x = (float)gx + u;
        const float y = (float)gy + v;
        const float x0 = floorf(x), x1 = x0 + 1.0f;
        const float y0 = floorf(y), y1 = y0 + 1.0f;

        const int x0c = (int)fminf(fmaxf(x0, 0.0f), Wm1);
        const int x1c = (int)fminf(fmaxf(x1, 0.0f), Wm1);
        const int y0c = (int)fminf(fmaxf(y0, 0.0f), Hm1);
        const int y1c = (int)fminf(fmaxf(y1, 0.0f), Hm1);

        const float wa = (x1 - x) * (y1 - y);
        const float wb = (x1 - x) * (y - y0);
        const float wc = (x - x0) * (y1 - y);
        const float wd = (x - x0) * (y - y0);

        const int pbx = min(x0c, W - 2);
        const int pby = min(y0c, H - 2);

        const float wlt = (x0c == pbx ? wa : 0.f) + (x1c == pbx ? wc : 0.f);
        const float wht = (x0c != pbx ? wa : 0.f) + (x1c != pbx ? wc : 0.f);
        const float wlb = (x0c == pbx ? wb : 0.f) + (x1c == pbx ? wd : 0.f);
        const float whb = (x0c != pbx ? wb : 0.f) + (x1c != pbx ? wd : 0.f);
        const bool t0 = (y0c == pby), t1 = (y1c == pby);
        wtl[k] = (t0 ? wlt : 0.f) + (t1 ? wlb : 0.f);
        wth[k] = (t0 ? wht : 0.f) + (t1 ? whb : 0.f);
        wbl[k] = (t0 ? 0.f : wlt) + (t1 ? 0.f : wlb);
        wbh[k] = (t0 ? 0.f : wht) + (t1 ? 0.f : whb);

        const int lxp = pbx - gx0;
        const int lyb = pby - gy0;
        enc[k] = (lxp >= 0 && lxp <= LW-2 && lyb >= 0 && lyb <= LH-2)
               ? (lyb * LW + lxp) : -1;
    }

    float* optr0 = out + pixk[0];
    float* optr1 = out + pixk[1];

    // ---- staging descriptors, computed once; lane-consecutive slots ----
    int spix[2], chrel[2], dst4[2];
    #pragma unroll
    for (int s = 0; s < 2; ++s) {
        const int idx = tid + s * SOFF;        // s=0: 0..1023, s=1: 416..1439
        const int ch  = idx / NV;
        const int rem = idx - ch * NV;
        const int rr  = rem / GPR;
        const int g   = rem - rr * GPR;
        const int yy  = min(max(gy0 + rr, 0), H - 1);
        const int xs  = min(max(gx0 + 4*g, 0), W - 4);  // group fully in/out
        chrel[s] = ch;
        spix[s]  = yy * W + xs;
        dst4[s]  = idx * 4;
    }

    const int nph = (C + CGB - 1) / CGB;
    const bool fast = ((W & 3) == 0) && ((tileX+1)*TSX <= W)
                   && ((tileY+1)*TSY <= H);

    // gather one phase from `cur`; stores via optr0/optr1
    auto gather2 = [&](const float* cur, int c0) {
        #pragma unroll
        for (int k = 0; k < 2; ++k) {
            const int e = enc[k];
            if (e == -2) continue;
            float* o = (k == 0) ? optr0 : optr1;
            if (__builtin_expect(e >= 0, 1)) {
                const float* b0 = cur + e;
                const float a0 = wtl[k], a1 = wth[k];
                const float a2 = wbl[k], a3 = wbh[k];
                o[0] = a0*b0[0] + a1*b0[1] + a2*b0[LW] + a3*b0[LW+1];
                if (c0 + 1 < C)
                    o[HW] = a0*b0[PLANE]   + a1*b0[PLANE+1]
                          + a2*b0[PLANE+LW] + a3*b0[PLANE+LW+1];
            } else {
                // rare out-of-halo flow: recompute + global gather
                // (extra global loads only make the later vmcnt stricter)
                const int pix = pixk[k];
                const int gy  = tileY * TSY + rw + k;
                const float u = flow[pix];
                const float v = flow[HW + pix];
                const float x = (float)gx + u;
                const float y = (float)gy + v;
                const float x0 = floorf(x), y0f = floorf(y);
                const int x0c = (int)fminf(fmaxf(x0, 0.f), Wm1);
                const int x1c = (int)fminf(fmaxf(x0 + 1.f, 0.f), Wm1);
                const int y0c = (int)fminf(fmaxf(y0f, 0.f), Hm1);
                const int y1c = (int)fminf(fmaxf(y0f + 1.f, 0.f), Hm1);
                const float wa = (x0 + 1.f - x) * (y0f + 1.f - y);
                const float wb = (x0 + 1.f - x) * (y - y0f);
                const float wc = (x - x0) * (y0f + 1.f - y);
                const float wd = (x - x0) * (y - y0f);
                for (int c = 0; c < CGB && c0 + c < C; ++c) {
                    const float* ic = img + (size_t)(c0 + c) * HW;
                    o[(size_t)c * HW] =
                          wa * ic[(size_t)y0c*W + x0c] + wb * ic[(size_t)y1c*W + x0c]
                        + wc * ic[(size_t)y0c*W + x1c] + wd * ic[(size_t)y1c*W + x1c];
                }
            }
        }
    };

    if (fast) {
        float* bA = &lds[0];          // gather target
        float* bB = &lds[BUFSZ];      // next
        float* bC = &lds[2*BUFSZ];    // stage target (2 ahead)

        // prologue: stage phases 0 and 1
        #pragma unroll
        for (int s = 0; s < 2; ++s) {
            const int chc = min(chrel[s], C - 1);
            GLOAD_LDS16(img + (size_t)chc * HW + spix[s], bA + dst4[s]);
        }
        #pragma unroll
        for (int s = 0; s < 2; ++s) {
            const int chc = min(CGB + chrel[s], C - 1);
            GLOAD_LDS16(img + (size_t)chc * HW + spix[s], bB + dst4[s]);
        }
        // D0 retired (D1's 2 ops may remain outstanding)
        asm volatile("s_waitcnt vmcnt(2)" ::: "memory");
        __builtin_amdgcn_s_barrier();
        __builtin_amdgcn_sched_barrier(0);

        for (int p = 0; p < nph; ++p) {
            const int c0 = p * CGB;

            // issue DMA for phase p+2 into bC (channel clamp -> uniform count;
            // past-the-end phases restage channel C-1: harmless L2 hits)
            {
                const int c0n = c0 + 2 * CGB;
                #pragma unroll
                for (int s = 0; s < 2; ++s) {
                    const int chc = min(c0n + chrel[s], C - 1);
                    GLOAD_LDS16(img + (size_t)chc * HW + spix[s], bC + dst4[s]);
                }
            }
            __builtin_amdgcn_sched_barrier(0);   // pin: DMAs before stores

            gather2(bA, c0);                     // 4 stores per thread

            __builtin_amdgcn_sched_barrier(0);   // pin: stores before wait

            if (p + 1 < nph) {
                // ops issued after D(p+1): S(p-1)x4 + D(p+2)x2 + S(p)x4 = 10
                // (phase 0: D(2)x2 + S(0)x4 = 6). In-order vmcnt => D(p+1)
                // retired; output stores stay in flight across the barrier.
                if (p == 0) {
                    asm volatile("s_waitcnt vmcnt(6)" ::: "memory");
                } else {
                    asm volatile("s_waitcnt vmcnt(10)" ::: "memory");
                }
                __builtin_amdgcn_sched_barrier(0);
                __builtin_amdgcn_s_barrier();
                __builtin_amdgcn_sched_barrier(0);
            }
            float* tmp = bA; bA = bB; bB = bC; bC = tmp;   // rotate
            optr0 += (size_t)CGB * HW;
            optr1 += (size_t)CGB * HW;
        }
    } else {
        // generic slow path (partial tiles / W%4!=0): scalar stage + full syncs
        for (int p = 0; p < nph; ++p) {
            const int c0 = p * CGB;
            __syncthreads();
            for (int i = tid; i < CGB * PLANE; i += NTHREADS) {
                const int ch  = i / PLANE;
                const int rem = i - ch * PLANE;
                const int rr  = rem / LW;
                const int cc  = rem - rr * LW;
                const int yy  = min(max(gy0 + rr, 0), H - 1);
                const int xx  = min(max(gx0 + cc, 0), W - 1);
                const int chc = min(c0 + ch, C - 1);
                lds[i] = img[(size_t)chc * HW + (size_t)yy * W + xx];
            }
            __syncthreads();
            gather2(&lds[0], c0);
            optr0 += (size_t)CGB * HW;
            optr1 += (size_t)CGB * HW;
        }
    }
}

extern "C" void kernel_launch(void* const* d_in, const int* in_sizes, int n_in,
                              void* d_out, int out_size, void* d_ws, size_t ws_size,
                              hipStream_t stream) {
    const float* img  = (const float*)d_in[0];
    const float* flow = (const float*)d_in[1];
    const int*   Hp   = (const int*)d_in[2];
    const int*   Wp   = (const int*)d_in[3];
    float* out = (float*)d_out;

    const int HW = in_sizes[1] / 2;    // flow is (1,2,H,W)
    const int C  = in_sizes[0] / HW;   // img is (1,C,H,W)

    // host doesn't know W,H (device scalars): launch with tile slack,
    // excess blocks exit on the in-kernel ntiles guard.
    const int grid = (HW + TSX * TSY - 1) / (TSX * TSY) + 64;
    warp_pipe4<<<grid, NTHREADS, 0, stream>>>(img, flow, Hp, Wp, out, HW, C);
}